// Round 1
// baseline (460.258 us; speedup 1.0000x reference)
//
#include <hip/hip_runtime.h>
#include <math.h>

// TopK router: logits = x @ W^T + bias; top-2; softmax over the 2; scatter.
// x: [N=16384, H=4096] fp32, W: [E=64, H=4096] fp32, bias: [64] fp32.
// d_out: [N*64] final (fp32) then [N*2] selected_experts written as floats.

constexpr int E_EXPERTS = 64;
constexpr int H_DIM = 4096;
constexpr int BLOCK = 256;
constexpr int ROWS = 32;     // rows per block
constexpr int KC = 128;      // K chunk staged in LDS
constexpr int LDW = KC + 4;  // padded leading dim (breaks bank aliasing)

__global__ __launch_bounds__(BLOCK) void topk_router_kernel(
    const float* __restrict__ x, const float* __restrict__ w,
    const float* __restrict__ bias, float* __restrict__ out_final,
    float* __restrict__ out_idx, int N) {
  __shared__ float Xs[ROWS][LDW];
  __shared__ float Ws[E_EXPERTS][LDW];

  const int tid = threadIdx.x;
  const int tid_e = tid & 15;   // expert-group 0..15 (owns experts tid_e+16j)
  const int tid_r = tid >> 4;   // row-group 0..15 (owns rows 2*tid_r, 2*tid_r+1)
  const int rowBase = blockIdx.x * ROWS;

  // 2 rows x 4 experts, each as float4 partial sums (k%4 phases) for accuracy.
  float4 acc[2][4];
#pragma unroll
  for (int r = 0; r < 2; ++r)
#pragma unroll
    for (int j = 0; j < 4; ++j) acc[r][j] = make_float4(0.f, 0.f, 0.f, 0.f);

  for (int k0 = 0; k0 < H_DIM; k0 += KC) {
    // Stage X tile: 32 rows x 128 = 1024 float4, 4 per thread. Coalesced.
#pragma unroll
    for (int i = 0; i < 4; ++i) {
      int s = tid + i * BLOCK;
      int row = s >> 5;      // /32 float4 per row
      int c4 = s & 31;
      float4 v = *reinterpret_cast<const float4*>(
          &x[(size_t)(rowBase + row) * H_DIM + k0 + c4 * 4]);
      *reinterpret_cast<float4*>(&Xs[row][c4 * 4]) = v;
    }
    // Stage W tile: 64 rows x 128 = 2048 float4, 8 per thread. Coalesced.
#pragma unroll
    for (int i = 0; i < 8; ++i) {
      int s = tid + i * BLOCK;
      int e = s >> 5;
      int c4 = s & 31;
      float4 v = *reinterpret_cast<const float4*>(
          &w[(size_t)e * H_DIM + k0 + c4 * 4]);
      *reinterpret_cast<float4*>(&Ws[e][c4 * 4]) = v;
    }
    __syncthreads();

#pragma unroll
    for (int k4 = 0; k4 < KC / 4; ++k4) {
      float4 xa0 = *reinterpret_cast<const float4*>(&Xs[tid_r * 2 + 0][k4 * 4]);
      float4 xa1 = *reinterpret_cast<const float4*>(&Xs[tid_r * 2 + 1][k4 * 4]);
#pragma unroll
      for (int j = 0; j < 4; ++j) {
        float4 wb =
            *reinterpret_cast<const float4*>(&Ws[tid_e + 16 * j][k4 * 4]);
        acc[0][j].x += xa0.x * wb.x;
        acc[0][j].y += xa0.y * wb.y;
        acc[0][j].z += xa0.z * wb.z;
        acc[0][j].w += xa0.w * wb.w;
        acc[1][j].x += xa1.x * wb.x;
        acc[1][j].y += xa1.y * wb.y;
        acc[1][j].z += xa1.z * wb.z;
        acc[1][j].w += xa1.w * wb.w;
      }
    }
    __syncthreads();
  }

  // Epilogue: per row, top-2 over 64 experts across the 16-lane expert group.
#pragma unroll
  for (int r = 0; r < 2; ++r) {
    const int n = rowBase + tid_r * 2 + r;

    float av = -INFINITY, bv = -INFINITY;
    int ai = E_EXPERTS, bi = E_EXPERTS;
#pragma unroll
    for (int j = 0; j < 4; ++j) {
      int e = tid_e + 16 * j;
      float4 a4 = acc[r][j];
      float v = (a4.x + a4.y) + (a4.z + a4.w) + bias[e];
      bool beats_a = (v > av) || (v == av && e < ai);
      bool beats_b = (v > bv) || (v == bv && e < bi);
      if (beats_a) {
        bv = av; bi = ai; av = v; ai = e;
      } else if (beats_b) {
        bv = v; bi = e;
      }
    }
    // Butterfly merge across the 16 lanes of this expert group.
#pragma unroll
    for (int d = 1; d < 16; d <<= 1) {
      float av2 = __shfl_xor(av, d);
      float bv2 = __shfl_xor(bv, d);
      int ai2 = __shfl_xor(ai, d);
      int bi2 = __shfl_xor(bi, d);
      bool afirst = (av > av2) || (av == av2 && ai < ai2);
      float na, nb;
      int nai, nbi;
      if (afirst) {
        na = av; nai = ai;
        bool t = (bv > av2) || (bv == av2 && bi < ai2);
        nb = t ? bv : av2;
        nbi = t ? bi : ai2;
      } else {
        na = av2; nai = ai2;
        bool t = (av > bv2) || (av == bv2 && ai < bi2);
        nb = t ? av : bv2;
        nbi = t ? ai : bi2;
      }
      av = na; ai = nai; bv = nb; bi = nbi;
    }

    // softmax over the two (descending) logits: p0 = 1/(1+e1), p1 = e1/(1+e1)
    float e1 = expf(bv - av);
    float denom = 1.0f + e1;
    float p0 = 1.0f / denom;
    float p1 = e1 / denom;

#pragma unroll
    for (int j = 0; j < 4; ++j) {
      int e = tid_e + 16 * j;
      float o = (e == ai) ? p0 : (e == bi) ? p1 : 0.0f;
      out_final[(size_t)n * E_EXPERTS + e] = o;
    }
    if (tid_e == 0) {
      out_idx[(size_t)n * 2 + 0] = (float)ai;
      out_idx[(size_t)n * 2 + 1] = (float)bi;
    }
  }
}

extern "C" void kernel_launch(void* const* d_in, const int* in_sizes, int n_in,
                              void* d_out, int out_size, void* d_ws,
                              size_t ws_size, hipStream_t stream) {
  const float* x = (const float*)d_in[0];
  const float* w = (const float*)d_in[1];
  const float* bias = (const float*)d_in[2];
  const int N = in_sizes[0] / H_DIM;  // 16384
  float* out_final = (float*)d_out;
  float* out_idx = out_final + (size_t)N * E_EXPERTS;

  dim3 grid(N / ROWS);
  dim3 block(BLOCK);
  topk_router_kernel<<<grid, block, 0, stream>>>(x, w, bias, out_final,
                                                 out_idx, N);
}